// Round 1
// baseline (21.448 us; speedup 1.0000x reference)
//
#include <hip/hip_runtime.h>

namespace {
constexpr int kH = 1024;
constexpr int kW = 2048;
constexpr int kB = 2;
constexpr int SMN = 1 << 20;  // sentinel for min (never selected)
constexpr int SMX = -1;       // sentinel for max (never selected)
}

__global__ __launch_bounds__(256) void boundary_edge_kernel(const int* __restrict__ lab,
                                                            int* __restrict__ out) {
    const int tid = blockIdx.x * 256 + threadIdx.x;
    const int xq  = tid & (kW / 4 - 1);   // 0..511
    const int row = tid >> 9;             // log2(kW/4) = 9 ; 0..B*H-1
    const int x0  = xq << 2;
    const int y   = row & (kH - 1);
    const int bi  = row >> 10;            // log2(kH) = 10
    const int* img = lab + (size_t)bi * kH * kW;

    // Register arrays: index i maps to column (x0 + i - pad) per row group.
    int mn0[4], mx0[4];  // dy=-2, span [x0,   x0+3]
    int mn4[4], mx4[4];  // dy=+2, span [x0,   x0+3]
    int mn1[6], mx1[6];  // dy=-1, span [x0-1, x0+4]
    int mn3[6], mx3[6];  // dy=+1, span [x0-1, x0+4]
    int mn2[8], mx2[8];  // dy= 0, span [x0-2, x0+5]

    const bool hasL = (x0 > 0);          // x0-1, x0-2 in bounds (x0 is 4-aligned)
    const bool hasR = (x0 < kW - 4);     // x0+4, x0+5 in bounds

    // dy = -2
    {
        const int yy = y - 2;
        if (yy >= 0) {
            const int4 v = *reinterpret_cast<const int4*>(img + (size_t)yy * kW + x0);
            mn0[0] = mx0[0] = v.x; mn0[1] = mx0[1] = v.y;
            mn0[2] = mx0[2] = v.z; mn0[3] = mx0[3] = v.w;
        } else {
#pragma unroll
            for (int i = 0; i < 4; ++i) { mn0[i] = SMN; mx0[i] = SMX; }
        }
    }
    // dy = +2
    {
        const int yy = y + 2;
        if (yy < kH) {
            const int4 v = *reinterpret_cast<const int4*>(img + (size_t)yy * kW + x0);
            mn4[0] = mx4[0] = v.x; mn4[1] = mx4[1] = v.y;
            mn4[2] = mx4[2] = v.z; mn4[3] = mx4[3] = v.w;
        } else {
#pragma unroll
            for (int i = 0; i < 4; ++i) { mn4[i] = SMN; mx4[i] = SMX; }
        }
    }
    // dy = -1
    {
        const int yy = y - 1;
        if (yy >= 0) {
            const int* rp = img + (size_t)yy * kW;
            const int4 v = *reinterpret_cast<const int4*>(rp + x0);
            mn1[1] = mx1[1] = v.x; mn1[2] = mx1[2] = v.y;
            mn1[3] = mx1[3] = v.z; mn1[4] = mx1[4] = v.w;
            if (hasL) { const int t = rp[x0 - 1]; mn1[0] = mx1[0] = t; }
            else      { mn1[0] = SMN; mx1[0] = SMX; }
            if (hasR) { const int t = rp[x0 + 4]; mn1[5] = mx1[5] = t; }
            else      { mn1[5] = SMN; mx1[5] = SMX; }
        } else {
#pragma unroll
            for (int i = 0; i < 6; ++i) { mn1[i] = SMN; mx1[i] = SMX; }
        }
    }
    // dy = +1
    {
        const int yy = y + 1;
        if (yy < kH) {
            const int* rp = img + (size_t)yy * kW;
            const int4 v = *reinterpret_cast<const int4*>(rp + x0);
            mn3[1] = mx3[1] = v.x; mn3[2] = mx3[2] = v.y;
            mn3[3] = mx3[3] = v.z; mn3[4] = mx3[4] = v.w;
            if (hasL) { const int t = rp[x0 - 1]; mn3[0] = mx3[0] = t; }
            else      { mn3[0] = SMN; mx3[0] = SMX; }
            if (hasR) { const int t = rp[x0 + 4]; mn3[5] = mx3[5] = t; }
            else      { mn3[5] = SMN; mx3[5] = SMX; }
        } else {
#pragma unroll
            for (int i = 0; i < 6; ++i) { mn3[i] = SMN; mx3[i] = SMX; }
        }
    }
    // dy = 0
    {
        const int* rp = img + (size_t)y * kW;
        const int4 v = *reinterpret_cast<const int4*>(rp + x0);
        mn2[2] = mx2[2] = v.x; mn2[3] = mx2[3] = v.y;
        mn2[4] = mx2[4] = v.z; mn2[5] = mx2[5] = v.w;
        if (hasL) {
            const int t0 = rp[x0 - 2]; const int t1 = rp[x0 - 1];
            mn2[0] = mx2[0] = t0; mn2[1] = mx2[1] = t1;
        } else {
            mn2[0] = SMN; mx2[0] = SMX; mn2[1] = SMN; mx2[1] = SMX;
        }
        if (hasR) {
            const int t0 = rp[x0 + 4]; const int t1 = rp[x0 + 5];
            mn2[6] = mx2[6] = t0; mn2[7] = mx2[7] = t1;
        } else {
            mn2[6] = SMN; mx2[6] = SMX; mn2[7] = SMN; mx2[7] = SMX;
        }
    }

    int res[4];
#pragma unroll
    for (int j = 0; j < 4; ++j) {
        // dy=0: 5 taps
        int mnv = min(mn2[j], min(min(mn2[j + 1], mn2[j + 2]), min(mn2[j + 3], mn2[j + 4])));
        int mxv = max(mx2[j], max(max(mx2[j + 1], mx2[j + 2]), max(mx2[j + 3], mx2[j + 4])));
        // dy=-1 / +1: 3 taps each
        mnv = min(mnv, min(mn1[j], min(mn1[j + 1], mn1[j + 2])));
        mxv = max(mxv, max(mx1[j], max(mx1[j + 1], mx1[j + 2])));
        mnv = min(mnv, min(mn3[j], min(mn3[j + 1], mn3[j + 2])));
        mxv = max(mxv, max(mx3[j], max(mx3[j + 1], mx3[j + 2])));
        // dy=-2 / +2: 1 tap each
        mnv = min(mnv, min(mn0[j], mn4[j]));
        mxv = max(mxv, max(mx0[j], mx4[j]));

        const int x = x0 + j;
        const bool border = (y <= 1) | (y >= kH - 2) | (x <= 1) | (x >= kW - 2);
        res[j] = (mxv >= 1 && (mnv != mxv || border)) ? 1 : 0;
    }

    *reinterpret_cast<int4*>(out + (size_t)row * kW + x0) =
        make_int4(res[0], res[1], res[2], res[3]);
}

extern "C" void kernel_launch(void* const* d_in, const int* in_sizes, int n_in,
                              void* d_out, int out_size, void* d_ws, size_t ws_size,
                              hipStream_t stream) {
    const int* lab = (const int*)d_in[0];
    int* out = (int*)d_out;
    // total threads = B*H*W/4 = 1,048,576 -> 4096 blocks of 256 (exact)
    const int total_threads = kB * kH * kW / 4;
    const int blocks = total_threads / 256;
    boundary_edge_kernel<<<dim3(blocks), dim3(256), 0, stream>>>(lab, out);
}

// Round 2
// 15.276 us; speedup vs baseline: 1.4040x; 1.4040x over previous
//
#include <hip/hip_runtime.h>

namespace {
constexpr int kH = 1024;
constexpr int kW = 2048;
constexpr int SMN = 1 << 20;  // min sentinel (never selected)
constexpr int SMX = -1;       // max sentinel (never selected)
}

// 4x4 output tile per thread. Disk(2) decomposed vertically:
//   dx=0  -> 5-tall column (v2), dx=+-1 -> 3-tall (v1), dx=+-2 -> 1-tall (v0).
// 8 input rows (y0-2 .. y0+5) serve 4 output rows (y0 .. y0+3).
__global__ __launch_bounds__(256) void boundary_edge_kernel(const int* __restrict__ lab,
                                                            int* __restrict__ out) {
    const int x0 = (blockIdx.x * 64 + threadIdx.x) * 4;   // 0..2044, 4-aligned
    const int y0 = (blockIdx.y * 4 + threadIdx.y) * 4;    // 0..1020, 4-aligned
    const int bi = blockIdx.z;
    const int* img = lab + (size_t)bi * kH * kW;

    const bool hasL = (x0 > 0);
    const bool hasR = (x0 < kW - 4);

    // Row j holds input row ry = y0 + j - 2.
    int cmn[8][4], cmx[8][4];    // center cols x0..x0+3   (all rows)
    int h1mn[8][2], h1mx[8][2];  // cols x0-1, x0+4        (rows 1..6)
    int h2mn[8][2], h2mx[8][2];  // cols x0-2, x0+5        (rows 2..5)

#pragma unroll
    for (int j = 0; j < 8; ++j) {
        const bool needH1 = (j >= 1) && (j <= 6);
        const bool needH2 = (j >= 2) && (j <= 5);
        const int ry = y0 + j - 2;
        if (ry >= 0 && ry < kH) {
            const int* rp = img + (size_t)ry * kW;
            const int4 v = *reinterpret_cast<const int4*>(rp + x0);
            cmn[j][0] = cmx[j][0] = v.x;
            cmn[j][1] = cmx[j][1] = v.y;
            cmn[j][2] = cmx[j][2] = v.z;
            cmn[j][3] = cmx[j][3] = v.w;
            if (needH2) {
                if (hasL) {
                    const int2 L = *reinterpret_cast<const int2*>(rp + x0 - 2);
                    h2mn[j][0] = h2mx[j][0] = L.x;
                    h1mn[j][0] = h1mx[j][0] = L.y;
                } else {
                    h2mn[j][0] = SMN; h2mx[j][0] = SMX;
                    h1mn[j][0] = SMN; h1mx[j][0] = SMX;
                }
                if (hasR) {
                    const int2 R = *reinterpret_cast<const int2*>(rp + x0 + 4);
                    h1mn[j][1] = h1mx[j][1] = R.x;
                    h2mn[j][1] = h2mx[j][1] = R.y;
                } else {
                    h1mn[j][1] = SMN; h1mx[j][1] = SMX;
                    h2mn[j][1] = SMN; h2mx[j][1] = SMX;
                }
            } else if (needH1) {
                if (hasL) { const int t = rp[x0 - 1]; h1mn[j][0] = h1mx[j][0] = t; }
                else      { h1mn[j][0] = SMN; h1mx[j][0] = SMX; }
                if (hasR) { const int t = rp[x0 + 4]; h1mn[j][1] = h1mx[j][1] = t; }
                else      { h1mn[j][1] = SMN; h1mx[j][1] = SMX; }
            }
        } else {
#pragma unroll
            for (int i = 0; i < 4; ++i) { cmn[j][i] = SMN; cmx[j][i] = SMX; }
            if (needH1) {
                h1mn[j][0] = SMN; h1mx[j][0] = SMX;
                h1mn[j][1] = SMN; h1mx[j][1] = SMX;
            }
            if (needH2) {
                h2mn[j][0] = SMN; h2mx[j][0] = SMX;
                h2mn[j][1] = SMN; h2mx[j][1] = SMX;
            }
        }
    }

    // Vertical partials over center columns: pairs pc[j] = rows (j, j+1).
    int pcmn[7][4], pcmx[7][4];
#pragma unroll
    for (int j = 0; j < 7; ++j)
#pragma unroll
        for (int i = 0; i < 4; ++i) {
            pcmn[j][i] = min(cmn[j][i], cmn[j + 1][i]);
            pcmx[j][i] = max(cmx[j][i], cmx[j + 1][i]);
        }

    // Pairs over the +-1 halo columns: rows (j, j+1), j = 1..5.
    int p1mn[6][2], p1mx[6][2];
#pragma unroll
    for (int j = 1; j < 6; ++j)
#pragma unroll
        for (int c = 0; c < 2; ++c) {
            p1mn[j][c] = min(h1mn[j][c], h1mn[j + 1][c]);
            p1mx[j][c] = max(h1mx[j][c], h1mx[j + 1][c]);
        }

    // x-border flags (x0 is 4-aligned so only the extreme tiles qualify)
    bool xb[4];
#pragma unroll
    for (int i = 0; i < 4; ++i) {
        const int x = x0 + i;
        xb[i] = (x <= 1) | (x >= kW - 2);
    }

#pragma unroll
    for (int k = 0; k < 4; ++k) {
        // v2: 5-row vertical min/max on center cols (rows k..k+4)
        int v2mn[4], v2mx[4];
#pragma unroll
        for (int i = 0; i < 4; ++i) {
            v2mn[i] = min(min(pcmn[k][i], pcmn[k + 2][i]), cmn[k + 4][i]);
            v2mx[i] = max(max(pcmx[k][i], pcmx[k + 2][i]), cmx[k + 4][i]);
        }
        // v1: 3-row vertical on 6 cols (x0-1 .. x0+4), rows k+1..k+3
        int v1mn[6], v1mx[6];
        v1mn[0] = min(p1mn[k + 1][0], h1mn[k + 3][0]);
        v1mx[0] = max(p1mx[k + 1][0], h1mx[k + 3][0]);
        v1mn[5] = min(p1mn[k + 1][1], h1mn[k + 3][1]);
        v1mx[5] = max(p1mx[k + 1][1], h1mx[k + 3][1]);
#pragma unroll
        for (int i = 0; i < 4; ++i) {
            v1mn[i + 1] = min(pcmn[k + 1][i], cmn[k + 3][i]);
            v1mx[i + 1] = max(pcmx[k + 1][i], cmx[k + 3][i]);
        }
        // v0: single row k+2, 8 cols (x0-2 .. x0+5)
        int v0mn[8], v0mx[8];
        v0mn[0] = h2mn[k + 2][0]; v0mx[0] = h2mx[k + 2][0];
        v0mn[1] = h1mn[k + 2][0]; v0mx[1] = h1mx[k + 2][0];
#pragma unroll
        for (int i = 0; i < 4; ++i) { v0mn[i + 2] = cmn[k + 2][i]; v0mx[i + 2] = cmx[k + 2][i]; }
        v0mn[6] = h1mn[k + 2][1]; v0mx[6] = h1mx[k + 2][1];
        v0mn[7] = h2mn[k + 2][1]; v0mx[7] = h2mx[k + 2][1];

        const int y = y0 + k;
        const bool yb = (y <= 1) | (y >= kH - 2);

        int res[4];
#pragma unroll
        for (int i = 0; i < 4; ++i) {
            const int mnv = min(min(v2mn[i], min(v1mn[i], v1mn[i + 2])),
                                min(v0mn[i], v0mn[i + 4]));
            const int mxv = max(max(v2mx[i], max(v1mx[i], v1mx[i + 2])),
                                max(v0mx[i], v0mx[i + 4]));
            const bool border = yb | xb[i];
            res[i] = (mxv >= 1 && (mnv != mxv || border)) ? 1 : 0;
        }
        *reinterpret_cast<int4*>(out + ((size_t)(bi * kH + y) * kW + x0)) =
            make_int4(res[0], res[1], res[2], res[3]);
    }
}

extern "C" void kernel_launch(void* const* d_in, const int* in_sizes, int n_in,
                              void* d_out, int out_size, void* d_ws, size_t ws_size,
                              hipStream_t stream) {
    const int* lab = (const int*)d_in[0];
    int* out = (int*)d_out;
    // 512 x-threads (x-tile=4), 256 y-threads (y-tile=4), 2 batches.
    dim3 block(64, 4, 1);
    dim3 grid(kW / (64 * 4), kH / (4 * 4), 2);  // (8, 64, 2)
    boundary_edge_kernel<<<grid, block, 0, stream>>>(lab, out);
}

// Round 3
// 12.771 us; speedup vs baseline: 1.6795x; 1.1962x over previous
//
#include <hip/hip_runtime.h>
#include <stdint.h>

namespace {
constexpr int kH = 1024;
constexpr int kW = 2048;
}

__device__ __forceinline__ uint32_t pk2(int lo, int hi) {
    // labels are 0..19 so no masking needed
    return (uint32_t)lo | ((uint32_t)hi << 16);
}
__device__ __forceinline__ uint32_t pkmin(uint32_t a, uint32_t b) {
    uint32_t d;
    asm("v_pk_min_i16 %0, %1, %2" : "=v"(d) : "v"(a), "v"(b));
    return d;
}
__device__ __forceinline__ uint32_t pkmax(uint32_t a, uint32_t b) {
    uint32_t d;
    asm("v_pk_max_i16 %0, %1, %2" : "=v"(d) : "v"(a), "v"(b));
    return d;
}

// 4x4 output tile per thread, horizontal-first disk decomposition with
// clamp-to-edge (replicating an edge pixel duplicates an in-disk value ->
// neutral for min/max). Per input row j (ry = y0+j-2):
//   r0 = packed center cols            (needed all 8 rows, dy=+-2 and feeds r1/r2)
//   r1 = min/max over dx in [-1,1]     (rows 1..6, dy=+-1)
//   r2 = min/max over dx in [-2,2]     (rows 2..5, dy=0)
// Output row k: combine r2[k+2], r1[k+1], r1[k+3], r0[k], r0[k+4].
__global__ __launch_bounds__(256) void boundary_edge_kernel(const int* __restrict__ lab,
                                                            int* __restrict__ out) {
    const int x0 = (blockIdx.x * 64 + threadIdx.x) * 4;   // 4-aligned
    const int y0 = (blockIdx.y * 4 + threadIdx.y) * 4;    // 4-aligned
    const int bi = blockIdx.z;
    const int* img = lab + (size_t)bi * kH * kW;

    const bool hasL = (x0 > 0);
    const bool hasR = (x0 < kW - 4);

    uint32_t r0a[8], r0b[8];                      // raw packed cols (01),(23)
    uint32_t r1mn01[8], r1mx01[8], r1mn23[8], r1mx23[8];
    uint32_t r2mn01[8], r2mx01[8], r2mn23[8], r2mx23[8];

#pragma unroll
    for (int j = 0; j < 8; ++j) {
        const bool needH1 = (j >= 1) && (j <= 6);
        const bool needH2 = (j >= 2) && (j <= 5);
        const int ry = y0 + j - 2;
        const int ryc = min(max(ry, 0), kH - 1);  // clamp-to-edge (neutral)
        const int* rp = img + (size_t)ryc * kW;
        const int4 v = *reinterpret_cast<const int4*>(rp + x0);

        int m2 = v.x, m1 = v.x, p4 = v.w, p5 = v.w;  // clamped defaults
        if (needH2) {
            if (hasL) { const int2 L = *reinterpret_cast<const int2*>(rp + x0 - 2); m2 = L.x; m1 = L.y; }
            if (hasR) { const int2 R = *reinterpret_cast<const int2*>(rp + x0 + 4); p4 = R.x; p5 = R.y; }
        } else if (needH1) {
            if (hasL) m1 = rp[x0 - 1];
            if (hasR) p4 = rp[x0 + 4];
        }

        const uint32_t A = pk2(v.x, v.y);
        const uint32_t B = pk2(v.z, v.w);
        r0a[j] = A;
        r0b[j] = B;
        if (needH1) {
            const uint32_t L1 = pk2(m1, v.x);   // dx=-1 taps for cols 0,1
            const uint32_t M  = pk2(v.y, v.z);  // dx=+1 for cols 0,1; dx=-1 for cols 2,3
            const uint32_t N  = pk2(v.w, p4);   // dx=+1 taps for cols 2,3
            r1mn01[j] = pkmin(pkmin(L1, A), M);
            r1mx01[j] = pkmax(pkmax(L1, A), M);
            r1mn23[j] = pkmin(pkmin(M, B), N);
            r1mx23[j] = pkmax(pkmax(M, B), N);
            if (needH2) {
                const uint32_t L2 = pk2(m2, m1);  // dx=-2 taps for cols 0,1
                const uint32_t P  = pk2(p4, p5);  // dx=+2 taps for cols 2,3
                r2mn01[j] = pkmin(r1mn01[j], pkmin(L2, B));
                r2mx01[j] = pkmax(r1mx01[j], pkmax(L2, B));
                r2mn23[j] = pkmin(r1mn23[j], pkmin(A, P));
                r2mx23[j] = pkmax(r1mx23[j], pkmax(A, P));
            }
        }
    }

    // x-border flags (x0 is 4-aligned so only extreme tiles qualify)
    bool xb[4];
#pragma unroll
    for (int i = 0; i < 4; ++i) {
        const int x = x0 + i;
        xb[i] = (x <= 1) | (x >= kW - 2);
    }

#pragma unroll
    for (int k = 0; k < 4; ++k) {
        const uint32_t mn01 = pkmin(pkmin(r2mn01[k + 2], pkmin(r1mn01[k + 1], r1mn01[k + 3])),
                                    pkmin(r0a[k], r0a[k + 4]));
        const uint32_t mx01 = pkmax(pkmax(r2mx01[k + 2], pkmax(r1mx01[k + 1], r1mx01[k + 3])),
                                    pkmax(r0a[k], r0a[k + 4]));
        const uint32_t mn23 = pkmin(pkmin(r2mn23[k + 2], pkmin(r1mn23[k + 1], r1mn23[k + 3])),
                                    pkmin(r0b[k], r0b[k + 4]));
        const uint32_t mx23 = pkmax(pkmax(r2mx23[k + 2], pkmax(r1mx23[k + 1], r1mx23[k + 3])),
                                    pkmax(r0b[k], r0b[k + 4]));

        const int y = y0 + k;
        const bool yb = (y <= 1) | (y >= kH - 2);

        const uint32_t d01 = mn01 ^ mx01;  // per-half nonzero iff mn != mx
        const uint32_t d23 = mn23 ^ mx23;

        int res[4];
        res[0] = ((mx01 & 0xFFFFu) != 0u && (((d01 & 0xFFFFu) != 0u) | yb | xb[0])) ? 1 : 0;
        res[1] = ((mx01 >> 16)     != 0u && (((d01 >> 16)     != 0u) | yb | xb[1])) ? 1 : 0;
        res[2] = ((mx23 & 0xFFFFu) != 0u && (((d23 & 0xFFFFu) != 0u) | yb | xb[2])) ? 1 : 0;
        res[3] = ((mx23 >> 16)     != 0u && (((d23 >> 16)     != 0u) | yb | xb[3])) ? 1 : 0;

        *reinterpret_cast<int4*>(out + ((size_t)(bi * kH + y) * kW + x0)) =
            make_int4(res[0], res[1], res[2], res[3]);
    }
}

extern "C" void kernel_launch(void* const* d_in, const int* in_sizes, int n_in,
                              void* d_out, int out_size, void* d_ws, size_t ws_size,
                              hipStream_t stream) {
    const int* lab = (const int*)d_in[0];
    int* out = (int*)d_out;
    dim3 block(64, 4, 1);
    dim3 grid(kW / (64 * 4), kH / (4 * 4), 2);  // (8, 64, 2)
    boundary_edge_kernel<<<grid, block, 0, stream>>>(lab, out);
}

// Round 4
// 10.524 us; speedup vs baseline: 2.0380x; 1.2135x over previous
//
#include <hip/hip_runtime.h>
#include <stdint.h>

namespace {
constexpr int kH = 1024;
constexpr int kW = 2048;
constexpr int kNBX = kW / 256;  // 8 x-blocks
}

typedef int v4i __attribute__((ext_vector_type(4)));

__device__ __forceinline__ uint32_t pk2(int lo, int hi) {
    // labels are 0..19, no masking needed
    return (uint32_t)lo | ((uint32_t)hi << 16);
}
__device__ __forceinline__ uint32_t pkmin(uint32_t a, uint32_t b) {
    uint32_t d;
    asm("v_pk_min_i16 %0, %1, %2" : "=v"(d) : "v"(a), "v"(b));
    return d;
}
__device__ __forceinline__ uint32_t pkmax(uint32_t a, uint32_t b) {
    uint32_t d;
    asm("v_pk_max_i16 %0, %1, %2" : "=v"(d) : "v"(a), "v"(b));
    return d;
}
// funnel: pk2(lo.hi16, hi.lo16) -> compiler emits v_alignbit_b32
__device__ __forceinline__ uint32_t algn(uint32_t hi, uint32_t lo) {
    return (lo >> 16) | (hi << 16);
}

// 4x4 tile/thread; one wave = 64 lanes covering 256 contiguous px of one row-group.
// Horizontal halos come from neighbor lanes' registers:
//   left pack pk2(m2,m1)  == left  lane's B = pk2(v.z,v.w)
//   right pack pk2(p4,p5) == right lane's A = pk2(v.x,v.y)
// Block-edge halos: lanes 0..7 load the 8 rows' left int2, lanes 8..15 the right
// int2 (one predicated load per thread), rows fetch them via constant-index shfl.
// Clamp-to-edge at true image borders is exact for a disk min/max stencil.
__global__ __launch_bounds__(256) void boundary_edge_kernel(const int* __restrict__ lab,
                                                            int* __restrict__ out) {
    const int lane = threadIdx.x;                       // one wave per threadIdx.y
    const int bx = blockIdx.x;
    const int x0 = (bx * 64 + lane) * 4;
    const int y0 = (blockIdx.y * 4 + threadIdx.y) * 4;
    const int bi = blockIdx.z;
    const int* img = lab + (size_t)bi * kH * kW;

    const bool hasL = (bx > 0);
    const bool hasR = (bx < kNBX - 1);

    // Single predicated edge-halo load (8B), distributed by row index.
    uint32_t hv = 0;
    {
        const int j = lane & 7;
        const int ry = min(max(y0 + j - 2, 0), kH - 1);
        const bool doL = (lane < 8) && hasL;
        const bool doR = (lane >= 8) && (lane < 16) && hasR;
        if (doL | doR) {
            const int xh = (lane < 8) ? (bx * 256 - 2) : (bx * 256 + 256);
            const int2 t = *reinterpret_cast<const int2*>(img + (size_t)ry * kW + xh);
            hv = pk2(t.x, t.y);  // left: (m2,m1); right: (p4,p5)
        }
    }

    uint32_t r0a[8], r0b[8];
    uint32_t r1mn01[8], r1mx01[8], r1mn23[8], r1mx23[8];
    uint32_t r2mn01[8], r2mx01[8], r2mn23[8], r2mx23[8];

#pragma unroll
    for (int j = 0; j < 8; ++j) {
        const int ry = min(max(y0 + j - 2, 0), kH - 1);  // clamp-to-edge (neutral)
        const int4 v = *reinterpret_cast<const int4*>(img + (size_t)ry * kW + x0);
        const uint32_t A = pk2(v.x, v.y);
        const uint32_t B = pk2(v.z, v.w);
        r0a[j] = A;
        r0b[j] = B;
        if (j >= 1 && j <= 6) {
            uint32_t Bl = __shfl_up(B, 1);    // pk2(m2,m1) for lanes 1..63
            uint32_t Ar = __shfl_down(A, 1);  // pk2(p4,p5) for lanes 0..62
            const uint32_t fL = hasL ? __shfl(hv, j)     : pk2(v.x, v.x);
            const uint32_t fR = hasR ? __shfl(hv, j + 8) : pk2(v.w, v.w);
            if (lane == 0)  Bl = fL;
            if (lane == 63) Ar = fR;

            const uint32_t L1 = algn(A, Bl);   // pk2(m1, v.x)
            const uint32_t M  = algn(B, A);    // pk2(v.y, v.z)
            const uint32_t N  = algn(Ar, B);   // pk2(v.w, p4)

            r1mn01[j] = pkmin(pkmin(L1, A), M);
            r1mx01[j] = pkmax(pkmax(L1, A), M);
            r1mn23[j] = pkmin(pkmin(M, B), N);
            r1mx23[j] = pkmax(pkmax(M, B), N);
            if (j >= 2 && j <= 5) {
                r2mn01[j] = pkmin(r1mn01[j], pkmin(Bl, B));
                r2mx01[j] = pkmax(r1mx01[j], pkmax(Bl, B));
                r2mn23[j] = pkmin(r1mn23[j], pkmin(A, Ar));
                r2mx23[j] = pkmax(r1mx23[j], pkmax(A, Ar));
            }
        }
    }

    // x-border flags (x0 is 4-aligned so only the extreme tiles qualify)
    bool xb[4];
#pragma unroll
    for (int i = 0; i < 4; ++i) {
        const int x = x0 + i;
        xb[i] = (x <= 1) | (x >= kW - 2);
    }

#pragma unroll
    for (int k = 0; k < 4; ++k) {
        const uint32_t mn01 = pkmin(pkmin(r2mn01[k + 2], pkmin(r1mn01[k + 1], r1mn01[k + 3])),
                                    pkmin(r0a[k], r0a[k + 4]));
        const uint32_t mx01 = pkmax(pkmax(r2mx01[k + 2], pkmax(r1mx01[k + 1], r1mx01[k + 3])),
                                    pkmax(r0a[k], r0a[k + 4]));
        const uint32_t mn23 = pkmin(pkmin(r2mn23[k + 2], pkmin(r1mn23[k + 1], r1mn23[k + 3])),
                                    pkmin(r0b[k], r0b[k + 4]));
        const uint32_t mx23 = pkmax(pkmax(r2mx23[k + 2], pkmax(r1mx23[k + 1], r1mx23[k + 3])),
                                    pkmax(r0b[k], r0b[k + 4]));

        const int y = y0 + k;
        const bool yb = (y <= 1) | (y >= kH - 2);

        const uint32_t d01 = mn01 ^ mx01;  // per-half nonzero iff mn != mx
        const uint32_t d23 = mn23 ^ mx23;

        v4i r;
        r.x = ((mx01 & 0xFFFFu) != 0u && (((d01 & 0xFFFFu) != 0u) | yb | xb[0])) ? 1 : 0;
        r.y = ((mx01 >> 16)     != 0u && (((d01 >> 16)     != 0u) | yb | xb[1])) ? 1 : 0;
        r.z = ((mx23 & 0xFFFFu) != 0u && (((d23 & 0xFFFFu) != 0u) | yb | xb[2])) ? 1 : 0;
        r.w = ((mx23 >> 16)     != 0u && (((d23 >> 16)     != 0u) | yb | xb[3])) ? 1 : 0;

        __builtin_nontemporal_store(r,
            reinterpret_cast<v4i*>(out + ((size_t)(bi * kH + y) * kW + x0)));
    }
}

extern "C" void kernel_launch(void* const* d_in, const int* in_sizes, int n_in,
                              void* d_out, int out_size, void* d_ws, size_t ws_size,
                              hipStream_t stream) {
    const int* lab = (const int*)d_in[0];
    int* out = (int*)d_out;
    dim3 block(64, 4, 1);
    dim3 grid(kW / 256, kH / 16, 2);  // (8, 64, 2)
    boundary_edge_kernel<<<grid, block, 0, stream>>>(lab, out);
}

// Round 5
// 10.475 us; speedup vs baseline: 2.0476x; 1.0047x over previous
//
#include <hip/hip_runtime.h>
#include <stdint.h>

namespace {
constexpr int kH = 1024;
constexpr int kW = 2048;
constexpr int kRows = 20;     // 16 output rows + 2*2 y-halo
constexpr int kStride = 264;  // ints per LDS row (256 + 8 pad; 1056 B, 16B-aligned)
}

__device__ __forceinline__ uint32_t pk2(int lo, int hi) {
    // labels 0..19 -> single v_lshl_or_b32
    return (uint32_t)lo | ((uint32_t)hi << 16);
}
__device__ __forceinline__ uint32_t pkmin(uint32_t a, uint32_t b) {
    uint32_t d;
    asm("v_pk_min_i16 %0, %1, %2" : "=v"(d) : "v"(a), "v"(b));
    return d;
}
__device__ __forceinline__ uint32_t pkmax(uint32_t a, uint32_t b) {
    uint32_t d;
    asm("v_pk_max_i16 %0, %1, %2" : "=v"(d) : "v"(a), "v"(b));
    return d;
}
// pk2(lo.hi16, hi.lo16) -> v_alignbit_b32
__device__ __forceinline__ uint32_t algn(uint32_t hi, uint32_t lo) {
    return (lo >> 16) | (hi << 16);
}

typedef int v4i __attribute__((ext_vector_type(4)));

// Block tile: 256 wide x 16 tall. 20 input rows staged to LDS via
// global_load_lds width-16 (1 KB per wave-instruction, zero VGPR per
// outstanding load). x-halo pairs (cols bx0-2..-1, bx0+256..+257) staged by
// wave 0 with plain loads (clamped to edge at image borders -- neutral for a
// disk min/max stencil). Compute: per thread 4x4 px, per row one ds_read_b128
// (center) + two ds_read_b64 (left/right pairs; lanes 0/63 pointer-select the
// halo arrays). Then the proven packed-i16 horizontal-first min/max pipeline.
__global__ __launch_bounds__(256) void boundary_edge_kernel(const int* __restrict__ lab,
                                                            int* __restrict__ out) {
    __shared__ int ctr[kRows][kStride];
    __shared__ int hL[kRows][2];
    __shared__ int hR[kRows][2];

    const int lane = threadIdx.x;  // one wave per threadIdx.y
    const int ty   = threadIdx.y;
    const int bx0  = blockIdx.x * 256;
    const int by0  = blockIdx.y * 16;
    const int bi   = blockIdx.z;
    const int* img = lab + (size_t)bi * kH * kW;

    // ---- Stage center rows: 5 DMA insts per wave --------------------------
#pragma unroll
    for (int rr = 0; rr < 5; ++rr) {
        const int r  = ty * 5 + rr;
        const int ry = min(max(by0 + r - 2, 0), kH - 1);  // clamp-to-edge
        const int* src = img + (size_t)ry * kW + bx0 + lane * 4;
        __builtin_amdgcn_global_load_lds(
            (const __attribute__((address_space(1))) void*)src,
            (__attribute__((address_space(3))) void*)&ctr[r][0],
            16, 0, 0);
    }
    // ---- Stage x-halo pairs (wave 0 only) ---------------------------------
    if (ty == 0) {
        if (lane < kRows) {
            const int r  = lane;
            const int ry = min(max(by0 + r - 2, 0), kH - 1);
            const size_t ro = (size_t)ry * kW;
            hL[r][0] = img[ro + max(bx0 - 2, 0)];
            hL[r][1] = img[ro + max(bx0 - 1, 0)];
        } else if (lane >= 32 && lane < 32 + kRows) {
            const int r  = lane - 32;
            const int ry = min(max(by0 + r - 2, 0), kH - 1);
            const size_t ro = (size_t)ry * kW;
            hR[r][0] = img[ro + min(bx0 + 256, kW - 1)];
            hR[r][1] = img[ro + min(bx0 + 257, kW - 1)];
        }
    }
    __syncthreads();  // compiler emits vmcnt(0) drain for the DMAs

    // ---- Compute: rows j=0..7 -> LDS rows r=ty*4+j ------------------------
    uint32_t r0a[8], r0b[8];
    uint32_t r1mn01[8], r1mx01[8], r1mn23[8], r1mx23[8];
    uint32_t r2mn01[8], r2mx01[8], r2mn23[8], r2mx23[8];

#pragma unroll
    for (int j = 0; j < 8; ++j) {
        const int r = ty * 4 + j;
        const int* cp = &ctr[r][lane * 4];
        const int4 v = *reinterpret_cast<const int4*>(cp);  // ds_read_b128
        const uint32_t A = pk2(v.x, v.y);
        const uint32_t B = pk2(v.z, v.w);
        r0a[j] = A;
        r0b[j] = B;
        if (j >= 1 && j <= 6) {
            const int2* lp = (lane == 0)  ? reinterpret_cast<const int2*>(&hL[r][0])
                                          : reinterpret_cast<const int2*>(cp - 2);
            const int2* rp = (lane == 63) ? reinterpret_cast<const int2*>(&hR[r][0])
                                          : reinterpret_cast<const int2*>(cp + 4);
            const int2 Lp = *lp;  // (m2, m1)
            const int2 Rp = *rp;  // (p4, p5)
            const uint32_t Bl = pk2(Lp.x, Lp.y);
            const uint32_t Ar = pk2(Rp.x, Rp.y);

            const uint32_t L1 = algn(A, Bl);   // (m1, v.x)
            const uint32_t M  = algn(B, A);    // (v.y, v.z)
            const uint32_t N  = algn(Ar, B);   // (v.w, p4)

            r1mn01[j] = pkmin(pkmin(L1, A), M);
            r1mx01[j] = pkmax(pkmax(L1, A), M);
            r1mn23[j] = pkmin(pkmin(M, B), N);
            r1mx23[j] = pkmax(pkmax(M, B), N);
            if (j >= 2 && j <= 5) {
                r2mn01[j] = pkmin(r1mn01[j], pkmin(Bl, B));
                r2mx01[j] = pkmax(r1mx01[j], pkmax(Bl, B));
                r2mn23[j] = pkmin(r1mn23[j], pkmin(A, Ar));
                r2mx23[j] = pkmax(r1mx23[j], pkmax(A, Ar));
            }
        }
    }

    // x-border flags
    bool xb[4];
#pragma unroll
    for (int i = 0; i < 4; ++i) {
        const int x = bx0 + lane * 4 + i;
        xb[i] = (x <= 1) | (x >= kW - 2);
    }

#pragma unroll
    for (int k = 0; k < 4; ++k) {
        const uint32_t mn01 = pkmin(pkmin(r2mn01[k + 2], pkmin(r1mn01[k + 1], r1mn01[k + 3])),
                                    pkmin(r0a[k], r0a[k + 4]));
        const uint32_t mx01 = pkmax(pkmax(r2mx01[k + 2], pkmax(r1mx01[k + 1], r1mx01[k + 3])),
                                    pkmax(r0a[k], r0a[k + 4]));
        const uint32_t mn23 = pkmin(pkmin(r2mn23[k + 2], pkmin(r1mn23[k + 1], r1mn23[k + 3])),
                                    pkmin(r0b[k], r0b[k + 4]));
        const uint32_t mx23 = pkmax(pkmax(r2mx23[k + 2], pkmax(r1mx23[k + 1], r1mx23[k + 3])),
                                    pkmax(r0b[k], r0b[k + 4]));

        const int y = by0 + ty * 4 + k;
        const bool yb = (y <= 1) | (y >= kH - 2);

        const uint32_t d01 = mn01 ^ mx01;  // per-half nonzero iff mn != mx
        const uint32_t d23 = mn23 ^ mx23;

        v4i r;
        r.x = ((mx01 & 0xFFFFu) != 0u && (((d01 & 0xFFFFu) != 0u) | yb | xb[0])) ? 1 : 0;
        r.y = ((mx01 >> 16)     != 0u && (((d01 >> 16)     != 0u) | yb | xb[1])) ? 1 : 0;
        r.z = ((mx23 & 0xFFFFu) != 0u && (((d23 & 0xFFFFu) != 0u) | yb | xb[2])) ? 1 : 0;
        r.w = ((mx23 >> 16)     != 0u && (((d23 >> 16)     != 0u) | yb | xb[3])) ? 1 : 0;

        __builtin_nontemporal_store(r,
            reinterpret_cast<v4i*>(out + ((size_t)(bi * kH + y) * kW + bx0 + lane * 4)));
    }
}

extern "C" void kernel_launch(void* const* d_in, const int* in_sizes, int n_in,
                              void* d_out, int out_size, void* d_ws, size_t ws_size,
                              hipStream_t stream) {
    const int* lab = (const int*)d_in[0];
    int* out = (int*)d_out;
    dim3 block(64, 4, 1);
    dim3 grid(kW / 256, kH / 16, 2);  // (8, 64, 2) = 1024 blocks, 4/CU
    boundary_edge_kernel<<<grid, block, 0, stream>>>(lab, out);
}